// Round 5
// baseline (2663.384 us; speedup 1.0000x reference)
//
#include <hip/hip_runtime.h>
#include <stdint.h>

#define L_ 12
#define B_ 8
#define T_ 512
#define D_ 768
#define H_ 12
#define DH_ 64
#define M_ 4096               // B_*T_ rows
#define DD_ (D_*D_)

typedef unsigned short u16;
typedef __bf16 bf16x8 __attribute__((ext_vector_type(8)));
typedef float f32x4 __attribute__((ext_vector_type(4)));

#define WAIT_VM(N) asm volatile("s_waitcnt vmcnt(" #N ")" ::: "memory")

static __device__ __forceinline__ u16 f2b(float f) {
  union { float f; unsigned u; } x; x.f = f;
  unsigned r = x.u + 0x7fffu + ((x.u >> 16) & 1u);   // RNE
  return (u16)(r >> 16);
}
static __device__ __forceinline__ void gload16(u16* lds, const u16* g) {
  // async global->LDS, 16B/lane; LDS dest is wave-uniform base + lane*16
  __builtin_amdgcn_global_load_lds((__attribute__((address_space(1))) void*)(g),
                                   (__attribute__((address_space(3))) void*)(lds), 16, 0, 0);
}
static __device__ __forceinline__ f32x4 mfma16(bf16x8 a, bf16x8 b, f32x4 c) {
  return __builtin_amdgcn_mfma_f32_16x16x32_bf16(a, b, c, 0, 0, 0);
}
static __device__ __forceinline__ bf16x8 ldfrag(const u16* p) {
  return *reinterpret_cast<const bf16x8*>(p);
}

// ---------------- init: f32 -> bf16 copies ----------------
__global__ void init_kernel(const float* __restrict__ qs, const float* __restrict__ hs,
                            u16* __restrict__ qsb, u16* __restrict__ hidb,
                            float* __restrict__ hidf, int n) {
  int i = blockIdx.x * 256 + threadIdx.x;
  if (i < n) {
    qsb[i] = f2b(qs[i]);
    float h = hs[i];
    hidb[i] = f2b(h);
    hidf[i] = h;
  }
}

// ---------------- per-layer weight transpose+convert: W[k][n] f32 -> Wt[n][k] bf16 ----------------
__global__ void wt_kernel(const float* W0, const float* W1, const float* W2,
                          const float* W3, const float* W4, u16* __restrict__ out) {
  int w = blockIdx.z;
  const float* W = (w == 0) ? W0 : (w == 1) ? W1 : (w == 2) ? W2 : (w == 3) ? W3 : W4;
  u16* O = out + (size_t)w * DD_;
  int tx = threadIdx.x, ty = threadIdx.y;           // (32,8)
  int nb = blockIdx.x * 32, kb = blockIdx.y * 32;
  __shared__ u16 tile[32][33];
  #pragma unroll
  for (int i = ty; i < 32; i += 8)
    tile[i][tx] = f2b(W[(size_t)(kb + i) * D_ + nb + tx]);   // coalesced in n
  __syncthreads();
  #pragma unroll
  for (int i = ty; i < 32; i += 8)
    O[(size_t)(nb + i) * D_ + kb + tx] = tile[tx][i];        // coalesced in k
}

// ---------------- GEMM core: C[4096x768] = A[4096x768] @ Wt^T + bias (+res) ----------------
// 128x128 tile, BK=32, 3-deep LDS pipeline with counted vmcnt (T3+T4) + raw s_barrier,
// XCD-aware bijective block swizzle (nwg=192, 192%8==0), setprio around MFMA (T5).
static __device__ void gemm_core(const u16* __restrict__ A, const u16* __restrict__ W,
                                 const float* __restrict__ bias, const float* __restrict__ res,
                                 float* __restrict__ outf, u16* __restrict__ outb) {
  __shared__ __align__(16) u16 lA[3][128 * 32];
  __shared__ __align__(16) u16 lB[3][128 * 32];
  const int tid = threadIdx.x;
  const int wave = tid >> 6, lane = tid & 63;
  const int wm = wave >> 1, wn = wave & 1;

  // XCD swizzle: consecutive blocks on one XCD share A-row panels + full B
  const int nbx = gridDim.x;                      // 6
  const int nwg = nbx * gridDim.y;                // 192 (per z-plane)
  const int orig = blockIdx.y * nbx + blockIdx.x;
  const int cpx = nwg >> 3;
  const int swz = (orig & 7) * cpx + (orig >> 3);
  const int m0 = (swz / nbx) * 128, n0 = (swz % nbx) * 128;
  const int lr = lane & 15, lg = lane >> 4;

  f32x4 acc[4][4];
  #pragma unroll
  for (int i = 0; i < 4; i++)
    #pragma unroll
    for (int j = 0; j < 4; j++) acc[i][j] = f32x4{0.f, 0.f, 0.f, 0.f};

  const int r0 = wave * 16 + (lane >> 2);   // staging row within 64-row half
  const int cb = (lane & 3) * 8;            // staging col (elems) within 32
  const u16* Ab = A + (size_t)(m0 + r0) * D_ + cb;
  const u16* Wb = W + (size_t)(n0 + r0) * D_ + cb;

  // 4 VMEM ops per wave per tile
#define STAGE(buf, k0_) do {                                        \
    gload16(lA[buf] + wave * 512,        Ab + (k0_));               \
    gload16(lA[buf] + 2048 + wave * 512, Ab + (size_t)64 * D_ + (k0_)); \
    gload16(lB[buf] + wave * 512,        Wb + (k0_));               \
    gload16(lB[buf] + 2048 + wave * 512, Wb + (size_t)64 * D_ + (k0_)); \
  } while (0)

  STAGE(0, 0);
  STAGE(1, 32);

  int cur = 0;
  for (int kt = 0; kt < 24; ++kt) {
    if (kt < 22) {
      int s = cur + 2; if (s >= 3) s -= 3;
      STAGE(s, (kt + 2) * 32);              // issue 2 tiles ahead
      WAIT_VM(8);                           // oldest 4 (this tile's) done; 8 stay in flight
    } else if (kt == 22) {
      WAIT_VM(4);
    } else {
      WAIT_VM(0);
    }
    __builtin_amdgcn_s_barrier();           // all waves' loads for buf cur landed
    __builtin_amdgcn_sched_barrier(0);
    bf16x8 af[4], bw[4];
    #pragma unroll
    for (int i = 0; i < 4; i++) {
      af[i] = ldfrag(lA[cur] + (wm * 64 + i * 16 + lr) * 32 + lg * 8);
      bw[i] = ldfrag(lB[cur] + (wn * 64 + i * 16 + lr) * 32 + lg * 8);
    }
    __builtin_amdgcn_s_setprio(1);
    #pragma unroll
    for (int i = 0; i < 4; i++)
      #pragma unroll
      for (int j = 0; j < 4; j++)
        acc[i][j] = mfma16(af[i], bw[j], acc[i][j]);
    __builtin_amdgcn_s_setprio(0);
    __builtin_amdgcn_s_barrier();           // WAR: reads of buf cur done before restage
    cur = (cur == 2) ? 0 : cur + 1;
  }
#undef STAGE

  // epilogue: C[row][col] ; row=(lane>>4)*4+r, col=lane&15 within fragment
  #pragma unroll
  for (int j = 0; j < 4; j++) {
    const int colg = n0 + wn * 64 + j * 16 + lr;
    const float bv = bias[colg];
    #pragma unroll
    for (int i = 0; i < 4; i++) {
      const int rowb = m0 + wm * 64 + i * 16 + lg * 4;
      #pragma unroll
      for (int r = 0; r < 4; r++) {
        float v = acc[i][j][r] + bv;
        const size_t off = (size_t)(rowb + r) * D_ + colg;
        if (res)  v += res[off];
        if (outf) outf[off] = v;
        if (outb) outb[off] = f2b(v);
      }
    }
  }
}

__global__ __launch_bounds__(256) void qkv_kernel(
    const u16* qsb, const u16* hidb,
    const u16* wq, const u16* wk, const u16* wv,
    const float* bq, const float* bk, const float* bv,
    u16* q, u16* k, u16* v) {
  const u16* A; const u16* W; const float* bias; u16* out;
  if (blockIdx.z == 0)      { A = qsb;  W = wq; bias = bq; out = q; }
  else if (blockIdx.z == 1) { A = hidb; W = wk; bias = bk; out = k; }
  else                      { A = hidb; W = wv; bias = bv; out = v; }
  gemm_core(A, W, bias, nullptr, nullptr, out);
}

__global__ __launch_bounds__(256) void o_kernel(const u16* A, const u16* W, const float* bias,
                                                const float* res, float* outf) {
  gemm_core(A, W, bias, res, outf, nullptr);
}

// ---------------- V transpose: [B,T,H,DH] -> [B*H, DH, T] ----------------
__global__ void vtrans_kernel(const u16* __restrict__ v, u16* __restrict__ vt) {
  int tx = threadIdx.x, ty = threadIdx.y;      // (32,8)
  int bh = blockIdx.z, b = bh / H_, h = bh % H_;
  int t0 = blockIdx.x * 32, d0 = blockIdx.y * 32;
  __shared__ u16 tile[32][33];
  #pragma unroll
  for (int i = ty; i < 32; i += 8)
    tile[i][tx] = v[(size_t)(b * T_ + t0 + i) * D_ + h * DH_ + d0 + tx];
  __syncthreads();
  #pragma unroll
  for (int i = ty; i < 32; i += 8)
    vt[((size_t)bh * DH_ + d0 + i) * T_ + t0 + tx] = tile[tx][i];
}

// ---------------- fused attention: per block (b,h, 64 q-rows), 4 waves x 16 rows ----------------
// 1-D grid 768: bh = id % 96 so id%8 == bh%8 -> the 8 q-blocks of one (b,h)
// land on the SAME XCD; its L2 serves the K/V re-reads (12 bh x 128KB = 1.5MB < 4MB).
// P LDS uses XOR swizzle (key ^ ((row&7)<<3)) to kill the stride-1024B 16-way conflict.
__global__ __launch_bounds__(256) void attn_kernel(const u16* __restrict__ q, const u16* __restrict__ k,
                                                   const u16* __restrict__ vt, const float* __restrict__ mask,
                                                   u16* __restrict__ ctx) {
  __shared__ __align__(16) u16 P[4 * 16 * 512];   // 64 KB: per-wave P[16][512] bf16
  const int tid = threadIdx.x, wave = tid >> 6, lane = tid & 63;
  const int id = blockIdx.x;
  const int bh = id % 96, qblk = id / 96;
  const int b = bh / H_, h = bh % H_;
  const int q0 = qblk * 64 + wave * 16;
  const int lr = lane & 15, lg = lane >> 4;

  // Q fragments (rows q0+lr, dh = s*32 + lg*8 + j)
  bf16x8 qa0, qa1;
  {
    const u16* qp = q + (size_t)(b * T_ + q0 + lr) * D_ + h * DH_ + lg * 8;
    qa0 = ldfrag(qp);
    qa1 = ldfrag(qp + 32);
  }

  // S = Q K^T : acc[nf] covers keys nf*16..+15, rows q0..q0+15
  f32x4 S[32];
  #pragma unroll
  for (int nf = 0; nf < 32; ++nf) {
    const u16* kp = k + (size_t)(b * T_ + nf * 16 + lr) * D_ + h * DH_ + lg * 8;
    bf16x8 kb0 = ldfrag(kp);
    bf16x8 kb1 = ldfrag(kp + 32);
    f32x4 a = {0.f, 0.f, 0.f, 0.f};
    a = mfma16(qa0, kb0, a);
    a = mfma16(qa1, kb1, a);
    S[nf] = a;
  }
  // scale + mask
  #pragma unroll
  for (int nf = 0; nf < 32; ++nf) {
    const float mk = mask[(size_t)b * T_ + nf * 16 + lr];
    #pragma unroll
    for (int r = 0; r < 4; r++) S[nf][r] = S[nf][r] * 0.125f + mk;
  }
  // softmax along keys: row = lg*4+r lives in the 16 lanes sharing lg
  float inv[4];
  #pragma unroll
  for (int r = 0; r < 4; r++) {
    float m = -1e30f;
    #pragma unroll
    for (int nf = 0; nf < 32; ++nf) m = fmaxf(m, S[nf][r]);
    #pragma unroll
    for (int d = 1; d <= 8; d <<= 1) m = fmaxf(m, __shfl_xor(m, d));
    float s = 0.f;
    #pragma unroll
    for (int nf = 0; nf < 32; ++nf) { float p = __expf(S[nf][r] - m); S[nf][r] = p; s += p; }
    #pragma unroll
    for (int d = 1; d <= 8; d <<= 1) s += __shfl_xor(s, d);
    inv[r] = 1.f / s;
  }
  // write P (bf16, normalized) to this wave's LDS region: [row][key ^ ((row&7)<<3)]
  u16* Pw = P + wave * (16 * 512);
  #pragma unroll
  for (int nf = 0; nf < 32; ++nf)
    #pragma unroll
    for (int r = 0; r < 4; r++) {
      const int row = lg * 4 + r;
      Pw[row * 512 + ((nf * 16 + lr) ^ ((row & 7) << 3))] = f2b(S[nf][r] * inv[r]);
    }

  // O = P V : A-frag from LDS P (k-contiguous, swizzled), B-frag from Vt (k-contiguous)
  f32x4 O[4] = { {0.f,0.f,0.f,0.f}, {0.f,0.f,0.f,0.f}, {0.f,0.f,0.f,0.f}, {0.f,0.f,0.f,0.f} };
  for (int ks = 0; ks < 16; ++ks) {
    bf16x8 pa = ldfrag(Pw + lr * 512 + ((ks * 32 + lg * 8) ^ ((lr & 7) << 3)));
    #pragma unroll
    for (int nf = 0; nf < 4; ++nf) {
      const u16* vp = vt + ((size_t)bh * DH_ + nf * 16 + lr) * T_ + ks * 32 + lg * 8;
      O[nf] = mfma16(pa, ldfrag(vp), O[nf]);
    }
  }
  // write ctx [B,T,D] bf16
  #pragma unroll
  for (int nf = 0; nf < 4; ++nf)
    #pragma unroll
    for (int r = 0; r < 4; r++) {
      const int row = q0 + lg * 4 + r;
      ctx[(size_t)(b * T_ + row) * D_ + h * DH_ + nf * 16 + lr] = f2b(O[nf][r]);
    }
}

// ---------------- LayerNorm: one wave per row (768 = 12*64) ----------------
__global__ __launch_bounds__(256) void ln_kernel(const float* __restrict__ y,
                                                 const float* __restrict__ w, const float* __restrict__ bp,
                                                 float* __restrict__ outf, u16* __restrict__ outb) {
  const int wave = threadIdx.x >> 6, lane = threadIdx.x & 63;
  const int row = blockIdx.x * 4 + wave;
  const float* yr = y + (size_t)row * D_;
  float x[12];
  #pragma unroll
  for (int i = 0; i < 12; i++) x[i] = yr[i * 64 + lane];
  float s = 0.f;
  #pragma unroll
  for (int i = 0; i < 12; i++) s += x[i];
  #pragma unroll
  for (int d = 1; d <= 32; d <<= 1) s += __shfl_xor(s, d);
  const float u = s * (1.f / D_);
  float v = 0.f;
  #pragma unroll
  for (int i = 0; i < 12; i++) { float t = x[i] - u; v += t * t; }
  #pragma unroll
  for (int d = 1; d <= 32; d <<= 1) v += __shfl_xor(v, d);
  const float rinv = rsqrtf(v * (1.f / D_) + 1e-12f);
  #pragma unroll
  for (int i = 0; i < 12; i++) {
    const int c = i * 64 + lane;
    const float o = w[c] * ((x[i] - u) * rinv) + bp[c];
    const size_t off = (size_t)row * D_ + c;
    outf[off] = o;
    outb[off] = f2b(o);
  }
}

extern "C" void kernel_launch(void* const* d_in, const int* in_sizes, int n_in,
                              void* d_out, int out_size, void* d_ws, size_t ws_size,
                              hipStream_t stream) {
  const float* qs   = (const float*)d_in[0];
  const float* hs   = (const float*)d_in[1];
  const float* mask = (const float*)d_in[2];
  const float* Wq   = (const float*)d_in[3];
  const float* bq   = (const float*)d_in[4];
  const float* Wk   = (const float*)d_in[5];
  const float* bk   = (const float*)d_in[6];
  const float* Wv   = (const float*)d_in[7];
  const float* bv   = (const float*)d_in[8];
  const float* Wo1  = (const float*)d_in[9];
  const float* bo1  = (const float*)d_in[10];
  const float* l1w  = (const float*)d_in[11];
  const float* l1b  = (const float*)d_in[12];
  const float* Wo2  = (const float*)d_in[13];
  const float* bo2  = (const float*)d_in[14];
  const float* l2w  = (const float*)d_in[15];
  const float* l2b  = (const float*)d_in[16];
  float* out = (float*)d_out;

  char* p = (char*)d_ws;
  auto alloc = [&](size_t bytes) { char* r = p; p += (bytes + 255) & ~(size_t)255; return r; };
  u16*   wt   = (u16*)alloc((size_t)5 * DD_ * 2);   // per-layer transposed bf16 weights
  u16*   qsb  = (u16*)alloc((size_t)M_ * D_ * 2);
  u16*   hidb = (u16*)alloc((size_t)M_ * D_ * 2);
  float* hidf = (float*)alloc((size_t)M_ * D_ * 4);
  u16*   qb   = (u16*)alloc((size_t)M_ * D_ * 2);
  u16*   kb_  = (u16*)alloc((size_t)M_ * D_ * 2);
  u16*   vb_  = (u16*)alloc((size_t)M_ * D_ * 2);
  u16*   vtb  = (u16*)alloc((size_t)M_ * D_ * 2);
  u16*   ctxb = (u16*)alloc((size_t)M_ * D_ * 2);
  float* y    = (float*)alloc((size_t)M_ * D_ * 4);
  float* aof  = (float*)alloc((size_t)M_ * D_ * 4);
  u16*   aob  = (u16*)alloc((size_t)M_ * D_ * 2);

  init_kernel<<<(M_ * D_ + 255) / 256, 256, 0, stream>>>(qs, hs, qsb, hidb, hidf, M_ * D_);

  for (int l = 0; l < L_; ++l) {
    const size_t wo = (size_t)l * DD_;
    wt_kernel<<<dim3(24, 24, 5), dim3(32, 8), 0, stream>>>(Wq + wo, Wk + wo, Wv + wo, Wo1 + wo, Wo2 + wo, wt);
    qkv_kernel<<<dim3(6, 32, 3), 256, 0, stream>>>(qsb, hidb,
        wt, wt + DD_, wt + 2 * DD_, bq + l * D_, bk + l * D_, bv + l * D_, qb, kb_, vb_);
    vtrans_kernel<<<dim3(16, 2, 96), dim3(32, 8), 0, stream>>>(vb_, vtb);
    attn_kernel<<<768, 256, 0, stream>>>(qb, kb_, vtb, mask, ctxb);
    o_kernel<<<dim3(6, 32), 256, 0, stream>>>(ctxb, wt + 3 * DD_, bo1 + l * D_, hidf, y);
    ln_kernel<<<1024, 256, 0, stream>>>(y, l1w + l * D_, l1b + l * D_, aof, aob);
    o_kernel<<<dim3(6, 32), 256, 0, stream>>>(aob, wt + 4 * DD_, bo2 + l * D_, aof, y);
    ln_kernel<<<1024, 256, 0, stream>>>(y, l2w + l * D_, l2b + l * D_,
                                        (l == L_ - 1) ? out : hidf, hidb);
  }
}

// Round 6
// 2063.251 us; speedup vs baseline: 1.2909x; 1.2909x over previous
//
#include <hip/hip_runtime.h>
#include <stdint.h>

#define L_ 12
#define B_ 8
#define T_ 512
#define D_ 768
#define H_ 12
#define DH_ 64
#define M_ 4096               // B_*T_ rows
#define DD_ (D_*D_)

typedef unsigned short u16;
typedef __bf16 bf16x8 __attribute__((ext_vector_type(8)));
typedef float f32x4 __attribute__((ext_vector_type(4)));

static __device__ __forceinline__ u16 f2b(float f) {
  union { float f; unsigned u; } x; x.f = f;
  unsigned r = x.u + 0x7fffu + ((x.u >> 16) & 1u);   // RNE
  return (u16)(r >> 16);
}
static __device__ __forceinline__ void gload16(u16* lds, const u16* g) {
  // async global->LDS, 16B/lane; LDS dest is wave-uniform base + lane*16
  __builtin_amdgcn_global_load_lds((__attribute__((address_space(1))) void*)(g),
                                   (__attribute__((address_space(3))) void*)(lds), 16, 0, 0);
}
static __device__ __forceinline__ f32x4 mfma16(bf16x8 a, bf16x8 b, f32x4 c) {
  return __builtin_amdgcn_mfma_f32_16x16x32_bf16(a, b, c, 0, 0, 0);
}
static __device__ __forceinline__ bf16x8 ldfrag(const u16* p) {
  return *reinterpret_cast<const bf16x8*>(p);
}

// ---------------- init: f32 -> bf16 copies ----------------
__global__ void init_kernel(const float* __restrict__ qs, const float* __restrict__ hs,
                            u16* __restrict__ qsb, u16* __restrict__ hidb,
                            float* __restrict__ hidf, int n) {
  int i = blockIdx.x * 256 + threadIdx.x;
  if (i < n) {
    qsb[i] = f2b(qs[i]);
    float h = hs[i];
    hidb[i] = f2b(h);
    hidf[i] = h;
  }
}

// ---------------- per-layer weight transpose+convert: W[k][n] f32 -> Wt[n][k] bf16 ----------------
__global__ void wt_kernel(const float* W0, const float* W1, const float* W2,
                          const float* W3, const float* W4, u16* __restrict__ out) {
  int w = blockIdx.z;
  const float* W = (w == 0) ? W0 : (w == 1) ? W1 : (w == 2) ? W2 : (w == 3) ? W3 : W4;
  u16* O = out + (size_t)w * DD_;
  int tx = threadIdx.x, ty = threadIdx.y;           // (32,8)
  int nb = blockIdx.x * 32, kb = blockIdx.y * 32;
  __shared__ u16 tile[32][33];
  #pragma unroll
  for (int i = ty; i < 32; i += 8)
    tile[i][tx] = f2b(W[(size_t)(kb + i) * D_ + nb + tx]);   // coalesced in n
  __syncthreads();
  #pragma unroll
  for (int i = ty; i < 32; i += 8)
    O[(size_t)(nb + i) * D_ + kb + tx] = tile[tx][i];        // coalesced in k
}

// ---------------- GEMM core: C[4096x768] = A[4096x768] @ Wt^T + bias (+res) ----------------
// 64x128 tile, BK=32, 2-buffer prefetch-first double-buffer (plain __syncthreads),
// T2 both-sides LDS swizzle (16B-unit col ^= (row>>1)&3; pre-swizzled global source,
// swizzled ds_read), XCD-aware bijective block swizzle (nwg=384, %8==0).
static __device__ void gemm_core(const u16* __restrict__ A, const u16* __restrict__ W,
                                 const float* __restrict__ bias, const float* __restrict__ res,
                                 float* __restrict__ outf, u16* __restrict__ outb) {
  __shared__ __align__(16) u16 lA[2][64 * 32];
  __shared__ __align__(16) u16 lB[2][128 * 32];
  const int tid = threadIdx.x;
  const int wave = tid >> 6, lane = tid & 63;
  const int wm = wave >> 1, wn = wave & 1;        // wave owns 32x64 of the 64x128 tile

  const int nbx = gridDim.x;                      // 6
  const int nwg = nbx * gridDim.y;                // 384 per z-plane
  const int orig = blockIdx.y * nbx + blockIdx.x;
  const int cpx = nwg >> 3;
  const int swz = (orig & 7) * cpx + (orig >> 3);
  const int m0 = (swz / nbx) * 64, n0 = (swz % nbx) * 128;
  const int lr = lane & 15, lg = lane >> 4;

  f32x4 acc[2][4];
  #pragma unroll
  for (int i = 0; i < 2; i++)
    #pragma unroll
    for (int j = 0; j < 4; j++) acc[i][j] = f32x4{0.f, 0.f, 0.f, 0.f};

  // staging: lane -> row wave*16 + (lane>>2); 16B-unit col (lane&3) pre-swizzled so
  // LDS[row][c] = G[row][c ^ ((row>>1)&3)]   (row bits 1,2 == lane bits 3,4)
  const int r0 = wave * 16 + (lane >> 2);
  const int cbs = (((lane & 3) ^ ((lane >> 3) & 3)) * 8);
  const u16* Ab = A + (size_t)(m0 + r0) * D_ + cbs;
  const u16* Wb = W + (size_t)(n0 + r0) * D_ + cbs;

  // 3 VMEM ops per wave per tile
#define STAGE(buf, k0_) do {                                         \
    gload16(lA[buf] + wave * 512,        Ab + (k0_));                \
    gload16(lB[buf] + wave * 512,        Wb + (k0_));                \
    gload16(lB[buf] + 2048 + wave * 512, Wb + (size_t)64 * D_ + (k0_)); \
  } while (0)

  STAGE(0, 0);
  __syncthreads();

  // ds_read swizzle: unit col = lg ^ ((row>>1)&3); row bits 1,2 come from lr
  const int rc = ((lg ^ ((lr >> 1) & 3)) << 3);

  int cur = 0;
  for (int kt = 0; kt < 24; ++kt) {
    if (kt < 23) STAGE(cur ^ 1, (kt + 1) * 32);   // prefetch next tile FIRST
    bf16x8 af[2], bw[4];
    #pragma unroll
    for (int i = 0; i < 2; i++)
      af[i] = ldfrag(lA[cur] + (wm * 32 + i * 16 + lr) * 32 + rc);
    #pragma unroll
    for (int j = 0; j < 4; j++)
      bw[j] = ldfrag(lB[cur] + (wn * 64 + j * 16 + lr) * 32 + rc);
    #pragma unroll
    for (int i = 0; i < 2; i++)
      #pragma unroll
      for (int j = 0; j < 4; j++)
        acc[i][j] = mfma16(af[i], bw[j], acc[i][j]);
    __syncthreads();   // drains vmcnt (prefetch overlapped with compute) + guards buffers
    cur ^= 1;
  }
#undef STAGE

  // epilogue: C[row][col] ; row=(lane>>4)*4+r, col=lane&15 within fragment
  #pragma unroll
  for (int j = 0; j < 4; j++) {
    const int colg = n0 + wn * 64 + j * 16 + lr;
    const float bv = bias[colg];
    #pragma unroll
    for (int i = 0; i < 2; i++) {
      const int rowb = m0 + wm * 32 + i * 16 + lg * 4;
      #pragma unroll
      for (int r = 0; r < 4; r++) {
        float v = acc[i][j][r] + bv;
        const size_t off = (size_t)(rowb + r) * D_ + colg;
        if (res)  v += res[off];
        if (outf) outf[off] = v;
        if (outb) outb[off] = f2b(v);
      }
    }
  }
}

__global__ __launch_bounds__(256) void qkv_kernel(
    const u16* qsb, const u16* hidb,
    const u16* wq, const u16* wk, const u16* wv,
    const float* bq, const float* bk, const float* bv,
    u16* q, u16* k, u16* v) {
  const u16* A; const u16* W; const float* bias; u16* out;
  if (blockIdx.z == 0)      { A = qsb;  W = wq; bias = bq; out = q; }
  else if (blockIdx.z == 1) { A = hidb; W = wk; bias = bk; out = k; }
  else                      { A = hidb; W = wv; bias = bv; out = v; }
  gemm_core(A, W, bias, nullptr, nullptr, out);
}

__global__ __launch_bounds__(256) void o_kernel(const u16* A, const u16* W, const float* bias,
                                                const float* res, float* outf) {
  gemm_core(A, W, bias, res, outf, nullptr);
}

// ---------------- V transpose: [B,T,H,DH] -> [B*H, DH, T] ----------------
__global__ void vtrans_kernel(const u16* __restrict__ v, u16* __restrict__ vt) {
  int tx = threadIdx.x, ty = threadIdx.y;      // (32,8)
  int bh = blockIdx.z, b = bh / H_, h = bh % H_;
  int t0 = blockIdx.x * 32, d0 = blockIdx.y * 32;
  __shared__ u16 tile[32][33];
  #pragma unroll
  for (int i = ty; i < 32; i += 8)
    tile[i][tx] = v[(size_t)(b * T_ + t0 + i) * D_ + h * DH_ + d0 + tx];
  __syncthreads();
  #pragma unroll
  for (int i = ty; i < 32; i += 8)
    vt[((size_t)bh * DH_ + d0 + i) * T_ + t0 + tx] = tile[tx][i];
}

// ---------------- fused attention: per block (b,h, 64 q-rows), 4 waves x 16 rows ----------------
// 1-D grid 768: bh = id % 96 so id%8 == bh%8 -> all 8 q-blocks of one (b,h) on the SAME XCD.
// P LDS XOR-swizzled (key ^ ((row&7)<<3)).
__global__ __launch_bounds__(256) void attn_kernel(const u16* __restrict__ q, const u16* __restrict__ k,
                                                   const u16* __restrict__ vt, const float* __restrict__ mask,
                                                   u16* __restrict__ ctx) {
  __shared__ __align__(16) u16 P[4 * 16 * 512];   // 64 KB: per-wave P[16][512] bf16
  const int tid = threadIdx.x, wave = tid >> 6, lane = tid & 63;
  const int id = blockIdx.x;
  const int bh = id % 96, qblk = id / 96;
  const int b = bh / H_, h = bh % H_;
  const int q0 = qblk * 64 + wave * 16;
  const int lr = lane & 15, lg = lane >> 4;

  bf16x8 qa0, qa1;
  {
    const u16* qp = q + (size_t)(b * T_ + q0 + lr) * D_ + h * DH_ + lg * 8;
    qa0 = ldfrag(qp);
    qa1 = ldfrag(qp + 32);
  }

  // S = Q K^T
  f32x4 S[32];
  #pragma unroll
  for (int nf = 0; nf < 32; ++nf) {
    const u16* kp = k + (size_t)(b * T_ + nf * 16 + lr) * D_ + h * DH_ + lg * 8;
    bf16x8 kb0 = ldfrag(kp);
    bf16x8 kb1 = ldfrag(kp + 32);
    f32x4 a = {0.f, 0.f, 0.f, 0.f};
    a = mfma16(qa0, kb0, a);
    a = mfma16(qa1, kb1, a);
    S[nf] = a;
  }
  #pragma unroll
  for (int nf = 0; nf < 32; ++nf) {
    const float mk = mask[(size_t)b * T_ + nf * 16 + lr];
    #pragma unroll
    for (int r = 0; r < 4; r++) S[nf][r] = S[nf][r] * 0.125f + mk;
  }
  float inv[4];
  #pragma unroll
  for (int r = 0; r < 4; r++) {
    float m = -1e30f;
    #pragma unroll
    for (int nf = 0; nf < 32; ++nf) m = fmaxf(m, S[nf][r]);
    #pragma unroll
    for (int d = 1; d <= 8; d <<= 1) m = fmaxf(m, __shfl_xor(m, d));
    float s = 0.f;
    #pragma unroll
    for (int nf = 0; nf < 32; ++nf) { float p = __expf(S[nf][r] - m); S[nf][r] = p; s += p; }
    #pragma unroll
    for (int d = 1; d <= 8; d <<= 1) s += __shfl_xor(s, d);
    inv[r] = 1.f / s;
  }
  u16* Pw = P + wave * (16 * 512);
  #pragma unroll
  for (int nf = 0; nf < 32; ++nf)
    #pragma unroll
    for (int r = 0; r < 4; r++) {
      const int row = lg * 4 + r;
      Pw[row * 512 + ((nf * 16 + lr) ^ ((row & 7) << 3))] = f2b(S[nf][r] * inv[r]);
    }

  f32x4 O[4] = { {0.f,0.f,0.f,0.f}, {0.f,0.f,0.f,0.f}, {0.f,0.f,0.f,0.f}, {0.f,0.f,0.f,0.f} };
  for (int ks = 0; ks < 16; ++ks) {
    bf16x8 pa = ldfrag(Pw + lr * 512 + ((ks * 32 + lg * 8) ^ ((lr & 7) << 3)));
    #pragma unroll
    for (int nf = 0; nf < 4; ++nf) {
      const u16* vp = vt + ((size_t)bh * DH_ + nf * 16 + lr) * T_ + ks * 32 + lg * 8;
      O[nf] = mfma16(pa, ldfrag(vp), O[nf]);
    }
  }
  #pragma unroll
  for (int nf = 0; nf < 4; ++nf)
    #pragma unroll
    for (int r = 0; r < 4; r++) {
      const int row = q0 + lg * 4 + r;
      ctx[(size_t)(b * T_ + row) * D_ + h * DH_ + nf * 16 + lr] = f2b(O[nf][r]);
    }
}

// ---------------- LayerNorm: one wave per row (768 = 12*64) ----------------
__global__ __launch_bounds__(256) void ln_kernel(const float* __restrict__ y,
                                                 const float* __restrict__ w, const float* __restrict__ bp,
                                                 float* __restrict__ outf, u16* __restrict__ outb) {
  const int wave = threadIdx.x >> 6, lane = threadIdx.x & 63;
  const int row = blockIdx.x * 4 + wave;
  const float* yr = y + (size_t)row * D_;
  float x[12];
  #pragma unroll
  for (int i = 0; i < 12; i++) x[i] = yr[i * 64 + lane];
  float s = 0.f;
  #pragma unroll
  for (int i = 0; i < 12; i++) s += x[i];
  #pragma unroll
  for (int d = 1; d <= 32; d <<= 1) s += __shfl_xor(s, d);
  const float u = s * (1.f / D_);
  float v = 0.f;
  #pragma unroll
  for (int i = 0; i < 12; i++) { float t = x[i] - u; v += t * t; }
  #pragma unroll
  for (int d = 1; d <= 32; d <<= 1) v += __shfl_xor(v, d);
  const float rinv = rsqrtf(v * (1.f / D_) + 1e-12f);
  #pragma unroll
  for (int i = 0; i < 12; i++) {
    const int c = i * 64 + lane;
    const float o = w[c] * ((x[i] - u) * rinv) + bp[c];
    const size_t off = (size_t)row * D_ + c;
    outf[off] = o;
    outb[off] = f2b(o);
  }
}

extern "C" void kernel_launch(void* const* d_in, const int* in_sizes, int n_in,
                              void* d_out, int out_size, void* d_ws, size_t ws_size,
                              hipStream_t stream) {
  const float* qs   = (const float*)d_in[0];
  const float* hs   = (const float*)d_in[1];
  const float* mask = (const float*)d_in[2];
  const float* Wq   = (const float*)d_in[3];
  const float* bq   = (const float*)d_in[4];
  const float* Wk   = (const float*)d_in[5];
  const float* bk   = (const float*)d_in[6];
  const float* Wv   = (const float*)d_in[7];
  const float* bv   = (const float*)d_in[8];
  const float* Wo1  = (const float*)d_in[9];
  const float* bo1  = (const float*)d_in[10];
  const float* l1w  = (const float*)d_in[11];
  const float* l1b  = (const float*)d_in[12];
  const float* Wo2  = (const float*)d_in[13];
  const float* bo2  = (const float*)d_in[14];
  const float* l2w  = (const float*)d_in[15];
  const float* l2b  = (const float*)d_in[16];
  float* out = (float*)d_out;

  char* p = (char*)d_ws;
  auto alloc = [&](size_t bytes) { char* r = p; p += (bytes + 255) & ~(size_t)255; return r; };
  u16*   wt   = (u16*)alloc((size_t)5 * DD_ * 2);   // per-layer transposed bf16 weights
  u16*   qsb  = (u16*)alloc((size_t)M_ * D_ * 2);
  u16*   hidb = (u16*)alloc((size_t)M_ * D_ * 2);
  float* hidf = (float*)alloc((size_t)M_ * D_ * 4);
  u16*   qb   = (u16*)alloc((size_t)M_ * D_ * 2);
  u16*   kb_  = (u16*)alloc((size_t)M_ * D_ * 2);
  u16*   vb_  = (u16*)alloc((size_t)M_ * D_ * 2);
  u16*   vtb  = (u16*)alloc((size_t)M_ * D_ * 2);
  u16*   ctxb = (u16*)alloc((size_t)M_ * D_ * 2);
  float* y    = (float*)alloc((size_t)M_ * D_ * 4);
  float* aof  = (float*)alloc((size_t)M_ * D_ * 4);
  u16*   aob  = (u16*)alloc((size_t)M_ * D_ * 2);

  init_kernel<<<(M_ * D_ + 255) / 256, 256, 0, stream>>>(qs, hs, qsb, hidb, hidf, M_ * D_);

  for (int l = 0; l < L_; ++l) {
    const size_t wo = (size_t)l * DD_;
    wt_kernel<<<dim3(24, 24, 5), dim3(32, 8), 0, stream>>>(Wq + wo, Wk + wo, Wv + wo, Wo1 + wo, Wo2 + wo, wt);
    qkv_kernel<<<dim3(6, 64, 3), 256, 0, stream>>>(qsb, hidb,
        wt, wt + DD_, wt + 2 * DD_, bq + l * D_, bk + l * D_, bv + l * D_, qb, kb_, vb_);
    vtrans_kernel<<<dim3(16, 2, 96), dim3(32, 8), 0, stream>>>(vb_, vtb);
    attn_kernel<<<768, 256, 0, stream>>>(qb, kb_, vtb, mask, ctxb);
    o_kernel<<<dim3(6, 64), 256, 0, stream>>>(ctxb, wt + 3 * DD_, bo1 + l * D_, hidf, y);
    ln_kernel<<<1024, 256, 0, stream>>>(y, l1w + l * D_, l1b + l * D_, aof, aob);
    o_kernel<<<dim3(6, 64), 256, 0, stream>>>(aob, wt + 4 * DD_, bo2 + l * D_, aof, y);
    ln_kernel<<<1024, 256, 0, stream>>>(y, l2w + l * D_, l2b + l * D_,
                                        (l == L_ - 1) ? out : hidf, hidb);
  }
}

// Round 8
// 1650.025 us; speedup vs baseline: 1.6141x; 1.2504x over previous
//
#include <hip/hip_runtime.h>
#include <stdint.h>

#define L_ 12
#define B_ 8
#define T_ 512
#define D_ 768
#define H_ 12
#define DH_ 64
#define M_ 4096               // B_*T_ rows
#define DD_ (D_*D_)

typedef unsigned short u16;
typedef __bf16 bf16x8 __attribute__((ext_vector_type(8)));
typedef float f32x4 __attribute__((ext_vector_type(4)));

static __device__ __forceinline__ u16 f2b(float f) {
  union { float f; unsigned u; } x; x.f = f;
  unsigned r = x.u + 0x7fffu + ((x.u >> 16) & 1u);   // RNE
  return (u16)(r >> 16);
}
static __device__ __forceinline__ void gload16(u16* lds, const u16* g) {
  // async global->LDS; LDS dest = wave-uniform base + lane*16B; global src per-lane
  __builtin_amdgcn_global_load_lds((__attribute__((address_space(1))) void*)(g),
                                   (__attribute__((address_space(3))) void*)(lds), 16, 0, 0);
}
static __device__ __forceinline__ f32x4 mfma16(bf16x8 a, bf16x8 b, f32x4 c) {
  return __builtin_amdgcn_mfma_f32_16x16x32_bf16(a, b, c, 0, 0, 0);
}
static __device__ __forceinline__ bf16x8 ldfrag(const u16* p) {
  return *reinterpret_cast<const bf16x8*>(p);
}

// ---------------- init: f32 -> bf16 copies ----------------
__global__ void init_kernel(const float* __restrict__ qs, const float* __restrict__ hs,
                            u16* __restrict__ qsb, u16* __restrict__ hidb,
                            float* __restrict__ hidf, int n) {
  int i = blockIdx.x * 256 + threadIdx.x;
  if (i < n) {
    qsb[i] = f2b(qs[i]);
    float h = hs[i];
    hidb[i] = f2b(h);
    hidf[i] = h;
  }
}

// ---------------- per-layer weight transpose+convert: W[k][n] f32 -> Wt[n][k] bf16 ----------------
__global__ void wt_kernel(const float* W0, const float* W1, const float* W2,
                          const float* W3, const float* W4, u16* __restrict__ out) {
  int w = blockIdx.z;
  const float* W = (w == 0) ? W0 : (w == 1) ? W1 : (w == 2) ? W2 : (w == 3) ? W3 : W4;
  u16* O = out + (size_t)w * DD_;
  int tx = threadIdx.x, ty = threadIdx.y;           // (32,8)
  int nb = blockIdx.x * 32, kb = blockIdx.y * 32;
  __shared__ u16 tile[32][33];
  #pragma unroll
  for (int i = ty; i < 32; i += 8)
    tile[i][tx] = f2b(W[(size_t)(kb + i) * D_ + nb + tx]);   // coalesced in n
  __syncthreads();
  #pragma unroll
  for (int i = ty; i < 32; i += 8)
    O[(size_t)(nb + i) * D_ + kb + tx] = tile[tx][i];        // coalesced in k
}

// ---------------- GEMM core: C[4096x768] = A[4096x768] @ Wt^T + bias (+res) ----------------
// 64x128 tile, BK=32, 2-buffer prefetch-first double-buffer, T2 both-sides LDS swizzle,
// XCD-aware bijective block swizzle (nwg=384, %8==0).   [unchanged: passing @2063us]
static __device__ void gemm_core(const u16* __restrict__ A, const u16* __restrict__ W,
                                 const float* __restrict__ bias, const float* __restrict__ res,
                                 float* __restrict__ outf, u16* __restrict__ outb) {
  __shared__ __align__(16) u16 lA[2][64 * 32];
  __shared__ __align__(16) u16 lB[2][128 * 32];
  const int tid = threadIdx.x;
  const int wave = tid >> 6, lane = tid & 63;
  const int wm = wave >> 1, wn = wave & 1;        // wave owns 32x64 of the 64x128 tile

  const int nbx = gridDim.x;                      // 6
  const int nwg = nbx * gridDim.y;                // 384 per z-plane
  const int orig = blockIdx.y * nbx + blockIdx.x;
  const int cpx = nwg >> 3;
  const int swz = (orig & 7) * cpx + (orig >> 3);
  const int m0 = (swz / nbx) * 64, n0 = (swz % nbx) * 128;
  const int lr = lane & 15, lg = lane >> 4;

  f32x4 acc[2][4];
  #pragma unroll
  for (int i = 0; i < 2; i++)
    #pragma unroll
    for (int j = 0; j < 4; j++) acc[i][j] = f32x4{0.f, 0.f, 0.f, 0.f};

  const int r0 = wave * 16 + (lane >> 2);
  const int cbs = (((lane & 3) ^ ((lane >> 3) & 3)) * 8);
  const u16* Ab = A + (size_t)(m0 + r0) * D_ + cbs;
  const u16* Wb = W + (size_t)(n0 + r0) * D_ + cbs;

#define STAGE(buf, k0_) do {                                         \
    gload16(lA[buf] + wave * 512,        Ab + (k0_));                \
    gload16(lB[buf] + wave * 512,        Wb + (k0_));                \
    gload16(lB[buf] + 2048 + wave * 512, Wb + (size_t)64 * D_ + (k0_)); \
  } while (0)

  STAGE(0, 0);
  __syncthreads();

  const int rc = ((lg ^ ((lr >> 1) & 3)) << 3);

  int cur = 0;
  for (int kt = 0; kt < 24; ++kt) {
    if (kt < 23) STAGE(cur ^ 1, (kt + 1) * 32);   // prefetch next tile FIRST
    bf16x8 af[2], bw[4];
    #pragma unroll
    for (int i = 0; i < 2; i++)
      af[i] = ldfrag(lA[cur] + (wm * 32 + i * 16 + lr) * 32 + rc);
    #pragma unroll
    for (int j = 0; j < 4; j++)
      bw[j] = ldfrag(lB[cur] + (wn * 64 + j * 16 + lr) * 32 + rc);
    #pragma unroll
    for (int i = 0; i < 2; i++)
      #pragma unroll
      for (int j = 0; j < 4; j++)
        acc[i][j] = mfma16(af[i], bw[j], acc[i][j]);
    __syncthreads();
    cur ^= 1;
  }
#undef STAGE

  #pragma unroll
  for (int j = 0; j < 4; j++) {
    const int colg = n0 + wn * 64 + j * 16 + lr;
    const float bv = bias[colg];
    #pragma unroll
    for (int i = 0; i < 2; i++) {
      const int rowb = m0 + wm * 32 + i * 16 + lg * 4;
      #pragma unroll
      for (int r = 0; r < 4; r++) {
        float v = acc[i][j][r] + bv;
        const size_t off = (size_t)(rowb + r) * D_ + colg;
        if (res)  v += res[off];
        if (outf) outf[off] = v;
        if (outb) outb[off] = f2b(v);
      }
    }
  }
}

__global__ __launch_bounds__(256) void qkv_kernel(
    const u16* qsb, const u16* hidb,
    const u16* wq, const u16* wk, const u16* wv,
    const float* bq, const float* bk, const float* bv,
    u16* q, u16* k, u16* v) {
  const u16* A; const u16* W; const float* bias; u16* out;
  if (blockIdx.z == 0)      { A = qsb;  W = wq; bias = bq; out = q; }
  else if (blockIdx.z == 1) { A = hidb; W = wk; bias = bk; out = k; }
  else                      { A = hidb; W = wv; bias = bv; out = v; }
  gemm_core(A, W, bias, nullptr, nullptr, out);
}

__global__ __launch_bounds__(256) void o_kernel(const u16* A, const u16* W, const float* bias,
                                                const float* res, float* outf) {
  gemm_core(A, W, bias, res, outf, nullptr);
}

// ---------------- V transpose: [B,T,H,DH] -> [B*H, DH, T] ----------------
__global__ void vtrans_kernel(const u16* __restrict__ v, u16* __restrict__ vt) {
  int tx = threadIdx.x, ty = threadIdx.y;      // (32,8)
  int bh = blockIdx.z, b = bh / H_, h = bh % H_;
  int t0 = blockIdx.x * 32, d0 = blockIdx.y * 32;
  __shared__ u16 tile[32][33];
  #pragma unroll
  for (int i = ty; i < 32; i += 8)
    tile[i][tx] = v[(size_t)(b * T_ + t0 + i) * D_ + h * DH_ + d0 + tx];
  __syncthreads();
  #pragma unroll
  for (int i = ty; i < 32; i += 8)
    vt[((size_t)bh * DH_ + d0 + i) * T_ + t0 + tx] = tile[tx][i];
}

// ---------------- flash attention: block = (b,h, 64 q-rows), 4 waves x 16 rows ----------------
// Online softmax over 8 tiles of 64 keys. K/V tiles cooperatively staged into LDS
// (global_load_lds, full double-buffer, 1 sync/tile, stage issued right after barrier).
// All LDS tiles 64-elem rows (128B): 16B-unit col ^= (row&7) swizzle (both sides).
// 1-D grid 768: bh = id%96 -> all 8 q-blocks of one (b,h) on the same XCD (L2 co-locate).
// LDS = 16+16+8 = 40KB -> 4 blocks/CU.
__global__ __launch_bounds__(256) void attn_kernel(const u16* __restrict__ q, const u16* __restrict__ k,
                                                   const u16* __restrict__ vt, const float* __restrict__ mask,
                                                   u16* __restrict__ ctx) {
  __shared__ __align__(16) u16 KT[2][64 * 64];   // [key][dh]
  __shared__ __align__(16) u16 VT[2][64 * 64];   // [dh][key]
  __shared__ __align__(16) u16 PT[4 * 16 * 64];  // per-wave [qrow][key]
  const int tid = threadIdx.x, wave = tid >> 6, lane = tid & 63;
  const int id = blockIdx.x;
  const int bh = id % 96, qblk = id / 96;
  const int b = bh / H_, h = bh % H_;
  const int q0 = qblk * 64 + wave * 16;
  const int lr = lane & 15, lg = lane >> 4;

  // Q fragments (rows q0+lr)
  bf16x8 qa0, qa1;
  {
    const u16* qp = q + (size_t)(b * T_ + q0 + lr) * D_ + h * DH_ + lg * 8;
    qa0 = ldfrag(qp);
    qa1 = ldfrag(qp + 32);
  }

  // staging: unit u = it*256 + wave*64 + lane; row r=u>>3, 16B-unit c=u&7, src col pre-swizzled
  const int su0 = wave * 64 + lane, su1 = 256 + wave * 64 + lane;
  const int sr0 = su0 >> 3, sc0 = ((su0 & 7) ^ (sr0 & 7)) << 3;
  const int sr1 = su1 >> 3, sc1 = ((su1 & 7) ^ (sr1 & 7)) << 3;
  const u16* kbase = k + (size_t)b * T_ * D_ + h * DH_;
  const u16* vbase = vt + (size_t)bh * DH_ * T_;

#define STAGEKV(buf, kt_) do {                                                         \
    gload16(KT[buf] + wave * 512,        kbase + (size_t)((kt_) * 64 + sr0) * D_ + sc0); \
    gload16(KT[buf] + 2048 + wave * 512, kbase + (size_t)((kt_) * 64 + sr1) * D_ + sc1); \
    gload16(VT[buf] + wave * 512,        vbase + (size_t)sr0 * T_ + (kt_) * 64 + sc0);   \
    gload16(VT[buf] + 2048 + wave * 512, vbase + (size_t)sr1 * T_ + (kt_) * 64 + sc1);   \
  } while (0)

  float mrow[4] = {-1e30f, -1e30f, -1e30f, -1e30f};
  float lrow[4] = {0.f, 0.f, 0.f, 0.f};
  f32x4 O[4] = { {0,0,0,0}, {0,0,0,0}, {0,0,0,0}, {0,0,0,0} };
  u16* Pw = PT + wave * 1024;

  STAGEKV(0, 0);
  int cur = 0;
  for (int kt = 0; kt < 8; ++kt) {
    __syncthreads();                       // drains stage(kt); buf cur ready; buf cur^1 readers done
    if (kt < 7) STAGEKV(cur ^ 1, kt + 1);  // lands under this tile's compute

    // S = Q K^T  (keys kt*64 .. +63)
    f32x4 S[4];
    #pragma unroll
    for (int nf = 0; nf < 4; ++nf) {
      const u16* kr = KT[cur] + (nf * 16 + lr) * 64;
      bf16x8 kb0 = ldfrag(kr + ((lg       ^ (lr & 7)) << 3));
      bf16x8 kb1 = ldfrag(kr + (((4 + lg) ^ (lr & 7)) << 3));
      f32x4 a = {0.f, 0.f, 0.f, 0.f};
      a = mfma16(qa0, kb0, a);
      a = mfma16(qa1, kb1, a);
      S[nf] = a;
    }
    #pragma unroll
    for (int nf = 0; nf < 4; ++nf) {
      const float mk = mask[(size_t)b * T_ + kt * 64 + nf * 16 + lr];
      #pragma unroll
      for (int r = 0; r < 4; r++) S[nf][r] = S[nf][r] * 0.125f + mk;
    }
    // online softmax per row (rows live across the 16-lane lr-group)
    #pragma unroll
    for (int r = 0; r < 4; r++) {
      float tm = fmaxf(fmaxf(S[0][r], S[1][r]), fmaxf(S[2][r], S[3][r]));
      #pragma unroll
      for (int d = 1; d <= 8; d <<= 1) tm = fmaxf(tm, __shfl_xor(tm, d));
      const float mn = fmaxf(mrow[r], tm);
      const float sc = __expf(mrow[r] - mn);
      float ts = 0.f;
      #pragma unroll
      for (int nf = 0; nf < 4; ++nf) { float pv = __expf(S[nf][r] - mn); S[nf][r] = pv; ts += pv; }
      #pragma unroll
      for (int d = 1; d <= 8; d <<= 1) ts += __shfl_xor(ts, d);
      lrow[r] = lrow[r] * sc + ts;
      mrow[r] = mn;
      #pragma unroll
      for (int nf = 0; nf < 4; ++nf) O[nf][r] *= sc;
    }
    // P tile -> LDS (per-wave private; same-wave DS ordering via lgkmcnt)
    #pragma unroll
    for (int nf = 0; nf < 4; ++nf)
      #pragma unroll
      for (int r = 0; r < 4; r++) {
        const int R = lg * 4 + r;
        Pw[R * 64 + ((((nf << 1) | (lr >> 3)) ^ (R & 7)) << 3) + (lr & 7)] = f2b(S[nf][r]);
      }
    // O += P V
    #pragma unroll
    for (int ks = 0; ks < 2; ++ks) {
      bf16x8 pa = ldfrag(Pw + lr * 64 + (((ks * 4 + lg) ^ (lr & 7)) << 3));
      #pragma unroll
      for (int nf = 0; nf < 4; ++nf) {
        bf16x8 vb = ldfrag(VT[cur] + (nf * 16 + lr) * 64 + (((ks * 4 + lg) ^ (lr & 7)) << 3));
        O[nf] = mfma16(pa, vb, O[nf]);
      }
    }
    cur ^= 1;
  }
#undef STAGEKV

  // epilogue: normalize and write ctx [B,T,D] bf16
  #pragma unroll
  for (int r = 0; r < 4; r++) {
    const float inv = 1.f / lrow[r];
    const int row = q0 + lg * 4 + r;
    #pragma unroll
    for (int nf = 0; nf < 4; ++nf)
      ctx[(size_t)(b * T_ + row) * D_ + h * DH_ + nf * 16 + lr] = f2b(O[nf][r] * inv);
  }
}

// ---------------- LayerNorm: one wave per row (768 = 12*64) ----------------
__global__ __launch_bounds__(256) void ln_kernel(const float* __restrict__ y,
                                                 const float* __restrict__ w, const float* __restrict__ bp,
                                                 float* __restrict__ outf, u16* __restrict__ outb) {
  const int wave = threadIdx.x >> 6, lane = threadIdx.x & 63;
  const int row = blockIdx.x * 4 + wave;
  const float* yr = y + (size_t)row * D_;
  float x[12];
  #pragma unroll
  for (int i = 0; i < 12; i++) x[i] = yr[i * 64 + lane];
  float s = 0.f;
  #pragma unroll
  for (int i = 0; i < 12; i++) s += x[i];
  #pragma unroll
  for (int d = 1; d <= 32; d <<= 1) s += __shfl_xor(s, d);
  const float u = s * (1.f / D_);
  float v = 0.f;
  #pragma unroll
  for (int i = 0; i < 12; i++) { float t = x[i] - u; v += t * t; }
  #pragma unroll
  for (int d = 1; d <= 32; d <<= 1) v += __shfl_xor(v, d);
  const float rinv = rsqrtf(v * (1.f / D_) + 1e-12f);
  #pragma unroll
  for (int i = 0; i < 12; i++) {
    const int c = i * 64 + lane;
    const float o = w[c] * ((x[i] - u) * rinv) + bp[c];
    const size_t off = (size_t)row * D_ + c;
    outf[off] = o;
    outb[off] = f2b(o);
  }
}

extern "C" void kernel_launch(void* const* d_in, const int* in_sizes, int n_in,
                              void* d_out, int out_size, void* d_ws, size_t ws_size,
                              hipStream_t stream) {
  const float* qs   = (const float*)d_in[0];
  const float* hs   = (const float*)d_in[1];
  const float* mask = (const float*)d_in[2];
  const float* Wq   = (const float*)d_in[3];
  const float* bq   = (const float*)d_in[4];
  const float* Wk   = (const float*)d_in[5];
  const float* bk   = (const float*)d_in[6];
  const float* Wv   = (const float*)d_in[7];
  const float* bv   = (const float*)d_in[8];
  const float* Wo1  = (const float*)d_in[9];
  const float* bo1  = (const float*)d_in[10];
  const float* l1w  = (const float*)d_in[11];
  const float* l1b  = (const float*)d_in[12];
  const float* Wo2  = (const float*)d_in[13];
  const float* bo2  = (const float*)d_in[14];
  const float* l2w  = (const float*)d_in[15];
  const float* l2b  = (const float*)d_in[16];
  float* out = (float*)d_out;

  char* p = (char*)d_ws;
  auto alloc = [&](size_t bytes) { char* r = p; p += (bytes + 255) & ~(size_t)255; return r; };
  u16*   wt   = (u16*)alloc((size_t)5 * DD_ * 2);   // per-layer transposed bf16 weights
  u16*   qsb  = (u16*)alloc((size_t)M_ * D_ * 2);
  u16*   hidb = (u16*)alloc((size_t)M_ * D_ * 2);
  float* hidf = (float*)alloc((size_t)M_ * D_ * 4);
  u16*   qb   = (u16*)alloc((size_t)M_ * D_ * 2);
  u16*   kb_  = (u16*)alloc((size_t)M_ * D_ * 2);
  u16*   vb_  = (u16*)alloc((size_t)M_ * D_ * 2);
  u16*   vtb  = (u16*)alloc((size_t)M_ * D_ * 2);
  u16*   ctxb = (u16*)alloc((size_t)M_ * D_ * 2);
  float* y    = (float*)alloc((size_t)M_ * D_ * 4);
  float* aof  = (float*)alloc((size_t)M_ * D_ * 4);
  u16*   aob  = (u16*)alloc((size_t)M_ * D_ * 2);

  init_kernel<<<(M_ * D_ + 255) / 256, 256, 0, stream>>>(qs, hs, qsb, hidb, hidf, M_ * D_);

  for (int l = 0; l < L_; ++l) {
    const size_t wo = (size_t)l * DD_;
    wt_kernel<<<dim3(24, 24, 5), dim3(32, 8), 0, stream>>>(Wq + wo, Wk + wo, Wv + wo, Wo1 + wo, Wo2 + wo, wt);
    qkv_kernel<<<dim3(6, 64, 3), 256, 0, stream>>>(qsb, hidb,
        wt, wt + DD_, wt + 2 * DD_, bq + l * D_, bk + l * D_, bv + l * D_, qb, kb_, vb_);
    vtrans_kernel<<<dim3(16, 2, 96), dim3(32, 8), 0, stream>>>(vb_, vtb);
    attn_kernel<<<768, 256, 0, stream>>>(qb, kb_, vtb, mask, ctxb);
    o_kernel<<<dim3(6, 64), 256, 0, stream>>>(ctxb, wt + 3 * DD_, bo1 + l * D_, hidf, y);
    ln_kernel<<<1024, 256, 0, stream>>>(y, l1w + l * D_, l1b + l * D_, aof, aob);
    o_kernel<<<dim3(6, 64), 256, 0, stream>>>(aob, wt + 4 * DD_, bo2 + l * D_, aof, y);
    ln_kernel<<<1024, 256, 0, stream>>>(y, l2w + l * D_, l2b + l * D_,
                                        (l == L_ - 1) ? out : hidf, hidb);
  }
}